// Round 1
// baseline (696.417 us; speedup 1.0000x reference)
//
#include <hip/hip_runtime.h>
#include <hip/hip_bf16.h>
#include <math.h>

// ---------------- constants ----------------
#define B_    32
#define NCLS_ 20
#define T_    2048
#define D_    2048
#define L_    128
#define NPAIR 16

// ws layout (float offsets)
#define OFF_SIM_LCS  0               // 32 * 128*128
#define OFF_SIM_M    524288          // 32 * 128*128
#define OFF_SIM_G    1048576         // 32 * 128*128
#define OFF_RN       1572864         // 5 * 4096  (lcs, fa_lo, fa_hi, fb_lo, fb_hi)
#define OFF_NFEAT    1593344         // 96 (n_i, n_c, n_b)
#define OFF_LCS_RES  1593440         // 32
#define OFF_FSD_RES  1593472         // 32
#define OFF_ACC      1593504         // 2 (guide_sum, sparse_sum)
#define WS_FLOATS    1593506

// ---------------- row-norm kernel ----------------
// one 64-thread block per row; recip=1 -> 1/sqrt(ss), else sqrt(ss)
__global__ __launch_bounds__(64) void norm_kernel(const float* __restrict__ src,
                                                  float* __restrict__ dst,
                                                  int rowlen, int rowstride,
                                                  int nrows, int recip) {
    int row = blockIdx.x;
    if (row >= nrows) return;
    const float* p = src + (size_t)row * rowstride;
    float s = 0.f;
    for (int k = threadIdx.x; k < rowlen; k += 64) {
        float v = p[k];
        s += v * v;
    }
    #pragma unroll
    for (int off = 32; off; off >>= 1) s += __shfl_down(s, off);
    if (threadIdx.x == 0) dst[row] = recip ? rsqrtf(s) : sqrtf(s);
}

// ---------------- similarity GEMM ----------------
// grid = (2, 2, 96): z = job, (x,y) = 64x64 tile of the 128x128 output.
// jobs 0..31  : LCS (0..15 pos, 16..31 neg), K=2048, transform s=max(0,(sim-.8)*5)
// jobs 32..63 : FSD act_act (pos),  (job-32): pair=idx/2, half=idx&1 -> m/g, K=1024
// jobs 64..95 : FSD act_bak (neg),  same layout, slots 16..31
#define KC 16
__global__ __launch_bounds__(256) void sim_kernel(const float* __restrict__ lcs,
                                                  const float* __restrict__ fa,
                                                  const float* __restrict__ fb,
                                                  const int* __restrict__ pos,
                                                  const int* __restrict__ neg,
                                                  float* __restrict__ ws) {
    const float* rn = ws + OFF_RN;
    int job = blockIdx.z;

    const float *Aptr, *Bptr, *rnA, *rnB;
    float* out;
    int K, mode;

    if (job < 32) {
        int pi = job & 15;
        const int* pp = (job >= 16) ? neg : pos;
        int p0 = pp[2 * pi], p1 = pp[2 * pi + 1];
        Aptr = lcs + (size_t)p0 * L_ * D_;
        Bptr = lcs + (size_t)p1 * L_ * D_;
        rnA = rn + p0 * L_;
        rnB = rn + p1 * L_;
        out = ws + OFF_SIM_LCS + (size_t)job * L_ * L_;
        K = D_; mode = 0;
    } else {
        int idx = job - 32;            // 0..63
        int isneg = idx >= 32;
        int l = idx & 31;
        int pi = l >> 1, half = l & 1;
        const int* pp = isneg ? neg : pos;
        int p0 = pp[2 * pi], p1 = pp[2 * pi + 1];
        const float* Bbase = isneg ? fb : fa;
        Aptr = fa + (size_t)p0 * L_ * D_ + half * 1024;
        Bptr = Bbase + (size_t)p1 * L_ * D_ + half * 1024;
        rnA = rn + 4096 + half * 4096 + p0 * L_;                      // fa_lo / fa_hi
        rnB = rn + 4096 + (isneg ? 8192 : 0) + half * 4096 + p1 * L_; // fa_* or fb_*
        int slot = (isneg ? 16 : 0) + pi;
        out = ws + (half ? OFF_SIM_G : OFF_SIM_M) + (size_t)slot * L_ * L_;
        K = 1024; mode = 1;
    }

    __shared__ float As[64][KC + 1];
    __shared__ float Bs[64][KC + 1];
    int tid = threadIdx.x;
    int tx = tid & 15, ty = tid >> 4;
    int i0 = blockIdx.y * 64, j0 = blockIdx.x * 64;

    float acc[4][4];
    #pragma unroll
    for (int m = 0; m < 4; ++m)
        #pragma unroll
        for (int n = 0; n < 4; ++n) acc[m][n] = 0.f;

    for (int k0 = 0; k0 < K; k0 += KC) {
        for (int l = tid; l < 64 * KC; l += 256) {
            int r = l >> 4, kk = l & (KC - 1);
            As[r][kk] = Aptr[(size_t)(i0 + r) * D_ + k0 + kk];
            Bs[r][kk] = Bptr[(size_t)(j0 + r) * D_ + k0 + kk];
        }
        __syncthreads();
        #pragma unroll
        for (int kk = 0; kk < KC; ++kk) {
            float a[4], b[4];
            #pragma unroll
            for (int m = 0; m < 4; ++m) a[m] = As[ty * 4 + m][kk];
            #pragma unroll
            for (int n = 0; n < 4; ++n) b[n] = Bs[tx * 4 + n][kk];
            #pragma unroll
            for (int m = 0; m < 4; ++m)
                #pragma unroll
                for (int n = 0; n < 4; ++n) acc[m][n] += a[m] * b[n];
        }
        __syncthreads();
    }

    #pragma unroll
    for (int m = 0; m < 4; ++m) {
        int i = i0 + ty * 4 + m;
        float ra = rnA[i];
        #pragma unroll
        for (int n = 0; n < 4; ++n) {
            int j = j0 + tx * 4 + n;
            float v = acc[m][n] * ra * rnB[j];
            if (mode == 0) v = fmaxf((v - 0.8f) * 5.0f, 0.f);
            out[i * L_ + j] = v;
        }
    }
}

// ---------------- LCS DP (skewed wavefront, thread-per-row) ----------------
__global__ __launch_bounds__(128) void lcs_dp_kernel(const float* __restrict__ ws_simlcs,
                                                     float* __restrict__ res) {
    int job = blockIdx.x;
    const float* S = ws_simlcs + (size_t)job * L_ * L_;
    __shared__ float sh[128];
    int r = threadIdx.x;
    float left = 0.f, diag = 0.f, last = 0.f;
    for (int t = 2; t <= 2 * L_; ++t) {
        int j = t - r - 1;
        float up = 0.f;
        if (r > 0 && j >= 1 && j <= L_) up = sh[r - 1];
        __syncthreads();
        if (j >= 1 && j <= L_) {
            float s = S[r * L_ + (j - 1)];
            float nw = (s > 0.5f) ? (diag + s) : fmaxf(up, left);
            diag = up;
            left = nw;
            last = nw;
            sh[r] = nw;
        }
        __syncthreads();
    }
    if (r == L_ - 1) res[job] = last;
}

// ---------------- FSD soft-DP ----------------
__global__ __launch_bounds__(128) void fsd_dp_kernel(const float* __restrict__ ws_m,
                                                     const float* __restrict__ ws_g,
                                                     float* __restrict__ res) {
    int job = blockIdx.x;
    const float* M = ws_m + (size_t)job * L_ * L_;
    const float* G = ws_g + (size_t)job * L_ * L_;
    __shared__ float sh[128];
    int r = threadIdx.x;
    float left = 0.f, diag = 0.f, last = 0.f;
    const float GA = 0.1f, RGA = 10.0f;
    for (int t = 2; t <= 2 * L_; ++t) {
        int j = t - r - 1;
        float up = 0.f;
        if (r > 0 && j >= 1 && j <= L_) up = sh[r - 1];
        __syncthreads();
        if (j >= 1 && j <= L_) {
            float m = M[r * L_ + (j - 1)];
            float g = G[r * L_ + (j - 1)];
            float a = diag, b = g + up, c = g + left;
            float mx = fmaxf(a, fmaxf(b, c));
            float lse = mx + GA * logf(expf((a - mx) * RGA) +
                                       expf((b - mx) * RGA) +
                                       expf((c - mx) * RGA));
            float nw = m + lse;
            diag = up;
            left = nw;
            last = nw;
            sh[r] = nw;
        }
        __syncthreads();
    }
    if (r == L_ - 1) res[job] = last;
}

// ---------------- guide + sparse partial sums ----------------
__global__ __launch_bounds__(256) void guide_sparse_kernel(const float* __restrict__ temp_att,
                                                           const float* __restrict__ temp_cas,
                                                           float* __restrict__ acc) {
    float g = 0.f, sp = 0.f;
    int n = B_ * T_;
    for (int idx = blockIdx.x * blockDim.x + threadIdx.x; idx < n;
         idx += gridDim.x * blockDim.x) {
        float cas = temp_cas[(size_t)idx * (NCLS_ + 1) + NCLS_];
        float a0 = temp_att[(size_t)idx * 3 + 0];
        float a1 = temp_att[(size_t)idx * 3 + 1];
        g += fabsf(1.f - cas - a0);
        sp += a0 + a1;
    }
    #pragma unroll
    for (int off = 32; off; off >>= 1) {
        g += __shfl_down(g, off);
        sp += __shfl_down(sp, off);
    }
    if ((threadIdx.x & 63) == 0) {
        atomicAdd(&acc[0], g);
        atomicAdd(&acc[1], sp);
    }
}

// ---------------- final combine (1 block, 64 threads) ----------------
__global__ __launch_bounds__(64) void final_kernel(const float* __restrict__ xi,
                                                   const float* __restrict__ xc,
                                                   const float* __restrict__ xb,
                                                   const float* __restrict__ vl,
                                                   const float* __restrict__ ws,
                                                   float* __restrict__ out) {
    const float* nfeat = ws + OFF_NFEAT;
    const float* lcs_res = ws + OFF_LCS_RES;
    const float* fsd_res = ws + OFF_FSD_RES;
    const float* acc = ws + OFF_ACC;
    int lane = threadIdx.x;
    float part = 0.f;

    if (lane < B_) {
        int b = lane;
        float sv = 0.f;
        for (int j = 0; j < NCLS_; ++j) sv += vl[b * NCLS_ + j];
        float inv_i = 1.f / sv;
        float inv_c = 1.f / (sv + 1.f);
        float si = 0.f, sc = 0.f;
        for (int j = 0; j < NCLS_; ++j) {
            float lab = vl[b * NCLS_ + j];
            if (lab != 0.f) {
                si += logf(xi[b * (NCLS_ + 1) + j] + 1e-45f) * lab * inv_i;
                sc += logf(xc[b * (NCLS_ + 1) + j] + 1e-45f) * lab * inv_c;
            }
        }
        sc += logf(xc[b * (NCLS_ + 1) + NCLS_] + 1e-45f) * inv_c;
        float sb = logf(xb[b * (NCLS_ + 1) + NCLS_] + 1e-45f);
        float cls = -(si + sc + sb) / (float)B_;

        float ni = nfeat[b], nc = nfeat[B_ + b], nb = nfeat[2 * B_ + b];
        float f1 = fmaxf(50.f - ni + nc, 0.f);
        float f2 = fmaxf(50.f - nc + nb, 0.f);
        float fv = f1 + f2 + nb;
        float feat = fv * fv / (float)B_;

        float sgn = (b < NPAIR) ? -1.f : 1.f;  // pos subtracted, neg added
        float lcs = sgn * lcs_res[b] / (float)NPAIR;
        float fsd = sgn * fsd_res[b] / (float)NPAIR;

        part = cls + 5e-5f * feat + 0.1f * (lcs + fsd);
    }
    #pragma unroll
    for (int off = 32; off; off >>= 1) part += __shfl_down(part, off);
    if (lane == 0) {
        float guide = acc[0] / (float)B_;
        float sparse = acc[1] / (float)B_;
        out[0] = part + guide + 2e-4f * sparse;
    }
}

// ---------------- launcher ----------------
extern "C" void kernel_launch(void* const* d_in, const int* in_sizes, int n_in,
                              void* d_out, int out_size, void* d_ws, size_t ws_size,
                              hipStream_t stream) {
    const float* act_inst_cls = (const float*)d_in[0];
    const float* act_cont_cls = (const float*)d_in[1];
    const float* act_back_cls = (const float*)d_in[2];
    const float* vid_label    = (const float*)d_in[3];
    const float* temp_att     = (const float*)d_in[4];
    const float* act_inst_feat= (const float*)d_in[5];
    const float* act_cont_feat= (const float*)d_in[6];
    const float* act_back_feat= (const float*)d_in[7];
    // d_in[8] = temp_cas
    const float* temp_cas     = (const float*)d_in[8];
    const float* lcs_candi    = (const float*)d_in[9];
    const float* fsd_act      = (const float*)d_in[10];
    const float* fsd_bak      = (const float*)d_in[11];
    const int*   pos_pair     = (const int*)d_in[12];
    const int*   neg_pair     = (const int*)d_in[13];

    float* ws = (float*)d_ws;
    float* out = (float*)d_out;

    // zero the two accumulators
    hipMemsetAsync(ws + OFF_ACC, 0, 2 * sizeof(float), stream);

    // reciprocal row norms for similarity
    float* rn = ws + OFF_RN;
    hipLaunchKernelGGL(norm_kernel, dim3(B_ * L_), dim3(64), 0, stream,
                       lcs_candi, rn, D_, D_, B_ * L_, 1);
    hipLaunchKernelGGL(norm_kernel, dim3(B_ * L_), dim3(64), 0, stream,
                       fsd_act, rn + 4096, 1024, D_, B_ * L_, 1);
    hipLaunchKernelGGL(norm_kernel, dim3(B_ * L_), dim3(64), 0, stream,
                       fsd_act + 1024, rn + 8192, 1024, D_, B_ * L_, 1);
    hipLaunchKernelGGL(norm_kernel, dim3(B_ * L_), dim3(64), 0, stream,
                       fsd_bak, rn + 12288, 1024, D_, B_ * L_, 1);
    hipLaunchKernelGGL(norm_kernel, dim3(B_ * L_), dim3(64), 0, stream,
                       fsd_bak + 1024, rn + 16384, 1024, D_, B_ * L_, 1);
    // feature norms (plain)
    float* nfeat = ws + OFF_NFEAT;
    hipLaunchKernelGGL(norm_kernel, dim3(B_), dim3(64), 0, stream,
                       act_inst_feat, nfeat, D_, D_, B_, 0);
    hipLaunchKernelGGL(norm_kernel, dim3(B_), dim3(64), 0, stream,
                       act_cont_feat, nfeat + B_, D_, D_, B_, 0);
    hipLaunchKernelGGL(norm_kernel, dim3(B_), dim3(64), 0, stream,
                       act_back_feat, nfeat + 2 * B_, D_, D_, B_, 0);

    // all 96 similarity matrices
    hipLaunchKernelGGL(sim_kernel, dim3(2, 2, 96), dim3(256), 0, stream,
                       lcs_candi, fsd_act, fsd_bak, pos_pair, neg_pair, ws);

    // DPs
    hipLaunchKernelGGL(lcs_dp_kernel, dim3(32), dim3(128), 0, stream,
                       ws + OFF_SIM_LCS, ws + OFF_LCS_RES);
    hipLaunchKernelGGL(fsd_dp_kernel, dim3(32), dim3(128), 0, stream,
                       ws + OFF_SIM_M, ws + OFF_SIM_G, ws + OFF_FSD_RES);

    // guide + sparse
    hipLaunchKernelGGL(guide_sparse_kernel, dim3(64), dim3(256), 0, stream,
                       temp_att, temp_cas, ws + OFF_ACC);

    // final combine
    hipLaunchKernelGGL(final_kernel, dim3(1), dim3(64), 0, stream,
                       act_inst_cls, act_cont_cls, act_back_cls, vid_label,
                       ws, out);
}

// Round 2
// 314.507 us; speedup vs baseline: 2.2143x; 2.2143x over previous
//
#include <hip/hip_runtime.h>
#include <hip/hip_bf16.h>
#include <math.h>

// ---------------- constants ----------------
#define B_    32
#define NCLS_ 20
#define T_    2048
#define D_    2048
#define L_    128
#define NPAIR 16

// ws layout (float offsets)
#define OFF_SIM_LCS  0               // 32 * 128*128
#define OFF_SIM_M    524288          // 32 * 128*128
#define OFF_SIM_G    1048576         // 32 * 128*128
#define OFF_RN       1572864         // 5 * 4096  (lcs, fa_lo, fa_hi, fb_lo, fb_hi)
#define OFF_NFEAT    1593344         // 96 (n_i, n_c, n_b)
#define OFF_LCS_RES  1593440         // 32
#define OFF_FSD_RES  1593472         // 32
#define OFF_ACC      1593504         // 2 (guide_sum, sparse_sum)

typedef __attribute__((ext_vector_type(8))) short bf16x8;
typedef __attribute__((ext_vector_type(4))) float f32x4;

__device__ __forceinline__ ushort f2bf(float f) {
    __hip_bfloat16 h = __float2bfloat16(f);
    return *reinterpret_cast<ushort*>(&h);
}

// ---------------- fused row-norm kernel (one launch) ----------------
// blocks 0..4095       : lcs rows, full D, rsqrt -> rn[b]
// blocks 4096..20479   : fsd halves (fa_lo, fa_hi, fb_lo, fb_hi), rsqrt -> rn[b]
// blocks 20480..20575  : feat rows (inst, cont, back), sqrt -> nfeat
__global__ __launch_bounds__(64) void norm_all_kernel(
        const float* __restrict__ lcs, const float* __restrict__ fa,
        const float* __restrict__ fb, const float* __restrict__ fi,
        const float* __restrict__ fc, const float* __restrict__ fbk,
        float* __restrict__ ws) {
    int b = blockIdx.x;
    const float* src; float* dst; int len4; int recip = 1;
    float* rn = ws + OFF_RN;
    if (b < 4096) {
        src = lcs + (size_t)b * 2048; dst = rn + b; len4 = 512;
    } else if (b < 20480) {
        int region = (b - 4096) >> 12;     // 0 fa_lo, 1 fa_hi, 2 fb_lo, 3 fb_hi
        int r = (b - 4096) & 4095;
        const float* base = (region < 2) ? fa : fb;
        src = base + (size_t)r * 2048 + (region & 1) * 1024;
        dst = rn + b; len4 = 256;
    } else {
        int r = b - 20480;
        const float* base = (r < 32) ? fi : (r < 64 ? fc : fbk);
        src = base + (size_t)(r & 31) * 2048;
        dst = ws + OFF_NFEAT + r; len4 = 512; recip = 0;
    }
    const float4* p = (const float4*)src;
    float s = 0.f;
    for (int i = threadIdx.x; i < len4; i += 64) {
        float4 v = p[i];
        s += v.x * v.x + v.y * v.y + v.z * v.z + v.w * v.w;
    }
    #pragma unroll
    for (int off = 32; off; off >>= 1) s += __shfl_down(s, off);
    if (threadIdx.x == 0) *dst = recip ? rsqrtf(s) : sqrtf(s);
}

// ---------------- MFMA similarity kernel ----------------
// 96 blocks (1 per job), 256 threads = 4 waves, each wave a 64x64 quadrant.
// jobs 0..31 LCS (K=2048), 32..95 FSD halves (K=1024).
__global__ __launch_bounds__(256) void sim_mfma_kernel(
        const float* __restrict__ lcs, const float* __restrict__ fa,
        const float* __restrict__ fb, const int* __restrict__ pos,
        const int* __restrict__ neg, float* __restrict__ ws) {
    const float* rn = ws + OFF_RN;
    int job = blockIdx.x;

    const float *Aptr, *Bptr, *rnA, *rnB;
    float* out;
    int K, mode;

    if (job < 32) {
        int pi = job & 15;
        const int* pp = (job >= 16) ? neg : pos;
        int p0 = pp[2 * pi], p1 = pp[2 * pi + 1];
        Aptr = lcs + (size_t)p0 * L_ * D_;
        Bptr = lcs + (size_t)p1 * L_ * D_;
        rnA = rn + p0 * L_;
        rnB = rn + p1 * L_;
        out = ws + OFF_SIM_LCS + (size_t)job * L_ * L_;
        K = 2048; mode = 0;
    } else {
        int idx = job - 32;            // 0..63
        int isneg = idx >= 32;
        int ll = idx & 31;
        int pi = ll >> 1, half = ll & 1;
        const int* pp = isneg ? neg : pos;
        int p0 = pp[2 * pi], p1 = pp[2 * pi + 1];
        const float* Bbase = isneg ? fb : fa;
        Aptr = fa + (size_t)p0 * L_ * D_ + half * 1024;
        Bptr = Bbase + (size_t)p1 * L_ * D_ + half * 1024;
        rnA = rn + 4096 + half * 4096 + p0 * L_;
        rnB = rn + 4096 + (isneg ? 8192 : 0) + half * 4096 + p1 * L_;
        int slot = (isneg ? 16 : 0) + pi;
        out = ws + (half ? OFF_SIM_G : OFF_SIM_M) + (size_t)slot * L_ * L_;
        K = 1024; mode = 1;
    }

    __shared__ ushort lA[128 * 64];
    __shared__ ushort lB[128 * 64];
    int tid = threadIdx.x;
    int lane = tid & 63;
    int w = tid >> 6;
    int wr = w >> 1, wc = w & 1;
    int lrow = lane & 15, lhk = lane >> 4;

    f32x4 acc[4][4];
    #pragma unroll
    for (int m = 0; m < 4; ++m)
        #pragma unroll
        for (int n = 0; n < 4; ++n)
            acc[m][n] = (f32x4){0.f, 0.f, 0.f, 0.f};

    for (int k0 = 0; k0 < K; k0 += 64) {
        __syncthreads();               // previous iter's reads done
        #pragma unroll
        for (int i = 0; i < 4; ++i) {
            int c = tid + i * 256;     // 0..1023
            int row = c >> 3, kb = c & 7;
            int idx = ((row * 64 + kb * 8) ^ ((row & 7) << 3));
            const float* sA = Aptr + (size_t)row * D_ + k0 + kb * 8;
            float4 a0 = *(const float4*)sA;
            float4 a1 = *(const float4*)(sA + 4);
            bf16x8 sv;
            sv[0] = (short)f2bf(a0.x); sv[1] = (short)f2bf(a0.y);
            sv[2] = (short)f2bf(a0.z); sv[3] = (short)f2bf(a0.w);
            sv[4] = (short)f2bf(a1.x); sv[5] = (short)f2bf(a1.y);
            sv[6] = (short)f2bf(a1.z); sv[7] = (short)f2bf(a1.w);
            *(bf16x8*)&lA[idx] = sv;
            const float* sB = Bptr + (size_t)row * D_ + k0 + kb * 8;
            float4 b0 = *(const float4*)sB;
            float4 b1 = *(const float4*)(sB + 4);
            bf16x8 sw;
            sw[0] = (short)f2bf(b0.x); sw[1] = (short)f2bf(b0.y);
            sw[2] = (short)f2bf(b0.z); sw[3] = (short)f2bf(b0.w);
            sw[4] = (short)f2bf(b1.x); sw[5] = (short)f2bf(b1.y);
            sw[6] = (short)f2bf(b1.z); sw[7] = (short)f2bf(b1.w);
            *(bf16x8*)&lB[idx] = sw;
        }
        __syncthreads();
        #pragma unroll
        for (int ks = 0; ks < 2; ++ks) {
            int kbase = ks * 32 + lhk * 8;
            bf16x8 afr[4], bfr[4];
            #pragma unroll
            for (int m = 0; m < 4; ++m) {
                int row = wr * 64 + m * 16 + lrow;
                int idx = ((row * 64 + kbase) ^ ((row & 7) << 3));
                afr[m] = *(const bf16x8*)&lA[idx];
            }
            #pragma unroll
            for (int n = 0; n < 4; ++n) {
                int row = wc * 64 + n * 16 + lrow;
                int idx = ((row * 64 + kbase) ^ ((row & 7) << 3));
                bfr[n] = *(const bf16x8*)&lB[idx];
            }
            #pragma unroll
            for (int m = 0; m < 4; ++m)
                #pragma unroll
                for (int n = 0; n < 4; ++n)
                    acc[m][n] = __builtin_amdgcn_mfma_f32_16x16x32_bf16(
                        afr[m], bfr[n], acc[m][n], 0, 0, 0);
        }
    }

    // epilogue: C/D layout col=lane&15, row=(lane>>4)*4+reg
    #pragma unroll
    for (int m = 0; m < 4; ++m) {
        #pragma unroll
        for (int n = 0; n < 4; ++n) {
            int jj = wc * 64 + n * 16 + lrow;
            float rbv = rnB[jj];
            #pragma unroll
            for (int r = 0; r < 4; ++r) {
                int ii = wr * 64 + m * 16 + lhk * 4 + r;
                float v = acc[m][n][r] * rnA[ii] * rbv;
                if (mode == 0) v = fmaxf((v - 0.8f) * 5.0f, 0.f);
                out[ii * L_ + jj] = v;
            }
        }
    }
}

// ---------------- LCS DP: wave-synchronous, 64 lanes x 2 rows ----------------
// lane l owns rows ra=2l, rb=2l+1 (0-indexed). Cell (r,j) at step t=r+j.
__global__ __launch_bounds__(64) void lcs_dp_kernel(const float* __restrict__ ws_simlcs,
                                                    float* __restrict__ res) {
    int job = blockIdx.x;
    const float* S = ws_simlcs + (size_t)job * L_ * L_;
    int l = threadIdx.x;
    int ra = 2 * l, rb = 2 * l + 1;
    const float* Sa = S + ra * L_;
    const float* Sb = S + rb * L_;
    float a = 0.f, a_prev = 0.f, b = 0.f, u_prev = 0.f;
    float sa_buf[8], sb_buf[8];
    #pragma unroll
    for (int p = 0; p < 8; ++p) {
        sa_buf[p] = Sa[min(max(p - ra, 0), 127)];
        sb_buf[p] = Sb[min(max(p - rb, 0), 127)];
    }
    #pragma unroll 8
    for (int t = 0; t < 256; ++t) {
        int slot = t & 7;
        float sa = sa_buf[slot], sb = sb_buf[slot];
        int ja = t - ra, jb = t - rb;
        float u = __shfl_up(b, 1);
        if (l == 0) u = 0.f;
        // row ra: diag=u_prev, up=u, left=a
        float newa = (sa > 0.5f) ? (u_prev + sa) : fmaxf(u, a);
        // row rb: diag=a_prev, up=a (pre-update), left=b
        float newb = (sb > 0.5f) ? (a_prev + sb) : fmaxf(a, b);
        a_prev = a;
        if (ja >= 0 && ja < 128) a = newa;
        if (jb >= 0 && jb < 128) b = newb;
        u_prev = u;
        sa_buf[slot] = Sa[min(max(t + 8 - ra, 0), 127)];
        sb_buf[slot] = Sb[min(max(t + 8 - rb, 0), 127)];
    }
    if (l == 63) res[job] = b;
}

// ---------------- FSD soft-DP: same skeleton ----------------
__global__ __launch_bounds__(64) void fsd_dp_kernel(const float* __restrict__ wsm,
                                                    const float* __restrict__ wsg,
                                                    float* __restrict__ res) {
    int job = blockIdx.x;
    const float* M = wsm + (size_t)job * L_ * L_;
    const float* G = wsg + (size_t)job * L_ * L_;
    int l = threadIdx.x;
    int ra = 2 * l, rb = 2 * l + 1;
    const float* Ma = M + ra * L_; const float* Mb = M + rb * L_;
    const float* Ga = G + ra * L_; const float* Gb = G + rb * L_;
    float a = 0.f, a_prev = 0.f, b = 0.f, u_prev = 0.f;
    float mab[8], gab[8], mbb[8], gbb[8];
    #pragma unroll
    for (int p = 0; p < 8; ++p) {
        int ja = min(max(p - ra, 0), 127), jb = min(max(p - rb, 0), 127);
        mab[p] = Ma[ja]; gab[p] = Ga[ja];
        mbb[p] = Mb[jb]; gbb[p] = Gb[jb];
    }
    #pragma unroll 8
    for (int t = 0; t < 256; ++t) {
        int slot = t & 7;
        float ma = mab[slot], ga = gab[slot], mb = mbb[slot], gb = gbb[slot];
        int ja = t - ra, jb = t - rb;
        float u = __shfl_up(b, 1);
        if (l == 0) u = 0.f;
        // row ra: diag=u_prev, up=u, left=a
        float x0 = u_prev, x1 = ga + u, x2 = ga + a;
        float mx = fmaxf(x0, fmaxf(x1, x2));
        float e0 = __expf((x0 - mx) * 10.f);
        float e1 = __expf((x1 - mx) * 10.f);
        float e2 = __expf((x2 - mx) * 10.f);
        float newa = ma + mx + 0.1f * __logf(e0 + e1 + e2);
        // row rb: diag=a_prev, up=a, left=b
        float y0 = a_prev, y1 = gb + a, y2 = gb + b;
        float my = fmaxf(y0, fmaxf(y1, y2));
        float f0 = __expf((y0 - my) * 10.f);
        float f1 = __expf((y1 - my) * 10.f);
        float f2 = __expf((y2 - my) * 10.f);
        float newb = mb + my + 0.1f * __logf(f0 + f1 + f2);
        a_prev = a;
        if (ja >= 0 && ja < 128) a = newa;
        if (jb >= 0 && jb < 128) b = newb;
        u_prev = u;
        int jan = min(max(t + 8 - ra, 0), 127), jbn = min(max(t + 8 - rb, 0), 127);
        mab[slot] = Ma[jan]; gab[slot] = Ga[jan];
        mbb[slot] = Mb[jbn]; gbb[slot] = Gb[jbn];
    }
    if (l == 63) res[job] = b;
}

// ---------------- guide + sparse partial sums ----------------
__global__ __launch_bounds__(256) void guide_sparse_kernel(const float* __restrict__ temp_att,
                                                           const float* __restrict__ temp_cas,
                                                           float* __restrict__ acc) {
    float g = 0.f, sp = 0.f;
    int n = B_ * T_;
    for (int idx = blockIdx.x * blockDim.x + threadIdx.x; idx < n;
         idx += gridDim.x * blockDim.x) {
        float cas = temp_cas[(size_t)idx * (NCLS_ + 1) + NCLS_];
        float a0 = temp_att[(size_t)idx * 3 + 0];
        float a1 = temp_att[(size_t)idx * 3 + 1];
        g += fabsf(1.f - cas - a0);
        sp += a0 + a1;
    }
    #pragma unroll
    for (int off = 32; off; off >>= 1) {
        g += __shfl_down(g, off);
        sp += __shfl_down(sp, off);
    }
    if ((threadIdx.x & 63) == 0) {
        atomicAdd(&acc[0], g);
        atomicAdd(&acc[1], sp);
    }
}

// ---------------- final combine (1 block, 64 threads) ----------------
__global__ __launch_bounds__(64) void final_kernel(const float* __restrict__ xi,
                                                   const float* __restrict__ xc,
                                                   const float* __restrict__ xb,
                                                   const float* __restrict__ vl,
                                                   const float* __restrict__ ws,
                                                   float* __restrict__ out) {
    const float* nfeat = ws + OFF_NFEAT;
    const float* lcs_res = ws + OFF_LCS_RES;
    const float* fsd_res = ws + OFF_FSD_RES;
    const float* acc = ws + OFF_ACC;
    int lane = threadIdx.x;
    float part = 0.f;

    if (lane < B_) {
        int b = lane;
        float sv = 0.f;
        for (int j = 0; j < NCLS_; ++j) sv += vl[b * NCLS_ + j];
        float inv_i = 1.f / sv;
        float inv_c = 1.f / (sv + 1.f);
        float si = 0.f, sc = 0.f;
        for (int j = 0; j < NCLS_; ++j) {
            float lab = vl[b * NCLS_ + j];
            if (lab != 0.f) {
                si += logf(xi[b * (NCLS_ + 1) + j] + 1e-45f) * lab * inv_i;
                sc += logf(xc[b * (NCLS_ + 1) + j] + 1e-45f) * lab * inv_c;
            }
        }
        sc += logf(xc[b * (NCLS_ + 1) + NCLS_] + 1e-45f) * inv_c;
        float sb = logf(xb[b * (NCLS_ + 1) + NCLS_] + 1e-45f);
        float cls = -(si + sc + sb) / (float)B_;

        float ni = nfeat[b], nc = nfeat[B_ + b], nb = nfeat[2 * B_ + b];
        float f1 = fmaxf(50.f - ni + nc, 0.f);
        float f2 = fmaxf(50.f - nc + nb, 0.f);
        float fv = f1 + f2 + nb;
        float feat = fv * fv / (float)B_;

        float sgn = (b < NPAIR) ? -1.f : 1.f;  // pos subtracted, neg added
        float lcs = sgn * lcs_res[b] / (float)NPAIR;
        float fsd = sgn * fsd_res[b] / (float)NPAIR;

        part = cls + 5e-5f * feat + 0.1f * (lcs + fsd);
    }
    #pragma unroll
    for (int off = 32; off; off >>= 1) part += __shfl_down(part, off);
    if (lane == 0) {
        float guide = acc[0] / (float)B_;
        float sparse = acc[1] / (float)B_;
        out[0] = part + guide + 2e-4f * sparse;
    }
}

// ---------------- launcher ----------------
extern "C" void kernel_launch(void* const* d_in, const int* in_sizes, int n_in,
                              void* d_out, int out_size, void* d_ws, size_t ws_size,
                              hipStream_t stream) {
    const float* act_inst_cls = (const float*)d_in[0];
    const float* act_cont_cls = (const float*)d_in[1];
    const float* act_back_cls = (const float*)d_in[2];
    const float* vid_label    = (const float*)d_in[3];
    const float* temp_att     = (const float*)d_in[4];
    const float* act_inst_feat= (const float*)d_in[5];
    const float* act_cont_feat= (const float*)d_in[6];
    const float* act_back_feat= (const float*)d_in[7];
    const float* temp_cas     = (const float*)d_in[8];
    const float* lcs_candi    = (const float*)d_in[9];
    const float* fsd_act      = (const float*)d_in[10];
    const float* fsd_bak      = (const float*)d_in[11];
    const int*   pos_pair     = (const int*)d_in[12];
    const int*   neg_pair     = (const int*)d_in[13];

    float* ws = (float*)d_ws;
    float* out = (float*)d_out;

    hipMemsetAsync(ws + OFF_ACC, 0, 2 * sizeof(float), stream);

    hipLaunchKernelGGL(norm_all_kernel, dim3(20576), dim3(64), 0, stream,
                       lcs_candi, fsd_act, fsd_bak,
                       act_inst_feat, act_cont_feat, act_back_feat, ws);

    hipLaunchKernelGGL(sim_mfma_kernel, dim3(96), dim3(256), 0, stream,
                       lcs_candi, fsd_act, fsd_bak, pos_pair, neg_pair, ws);

    hipLaunchKernelGGL(lcs_dp_kernel, dim3(32), dim3(64), 0, stream,
                       ws + OFF_SIM_LCS, ws + OFF_LCS_RES);
    hipLaunchKernelGGL(fsd_dp_kernel, dim3(32), dim3(64), 0, stream,
                       ws + OFF_SIM_M, ws + OFF_SIM_G, ws + OFF_FSD_RES);

    hipLaunchKernelGGL(guide_sparse_kernel, dim3(64), dim3(256), 0, stream,
                       temp_att, temp_cas, ws + OFF_ACC);

    hipLaunchKernelGGL(final_kernel, dim3(1), dim3(64), 0, stream,
                       act_inst_cls, act_cont_cls, act_back_cls, vid_label,
                       ws, out);
}

// Round 3
// 279.949 us; speedup vs baseline: 2.4877x; 1.1234x over previous
//
#include <hip/hip_runtime.h>
#include <hip/hip_bf16.h>
#include <math.h>

// ---------------- constants ----------------
#define B_    32
#define NCLS_ 20
#define T_    2048
#define D_    2048
#define L_    128
#define NPAIR 16

// ws layout (float offsets)
#define OFF_LCS_PART 0               // 4 slices * 32 jobs * 16384
#define OFF_M_PART   2097152         // 2 slices * 32 * 16384
#define OFF_G_PART   3145728         // 2 slices * 32 * 16384
#define OFF_RN       4194304         // 5 * 4096 (lcs, fa_lo, fa_hi, fb_lo, fb_hi)
#define OFF_NFEAT    4214784         // 96
#define OFF_LCS_RES  4214880         // 32
#define OFF_FSD_RES  4214912         // 32
#define OFF_ACC      4214944         // 2
#define SLICE_STRIDE 524288          // 32*16384

typedef __attribute__((ext_vector_type(8))) short bf16x8;
typedef __attribute__((ext_vector_type(4))) float f32x4;

__device__ __forceinline__ ushort f2bf(float f) {
    __hip_bfloat16 h = __float2bfloat16(f);
    return *reinterpret_cast<ushort*>(&h);
}

// ---------------- fused row-norm kernel ----------------
__global__ __launch_bounds__(64) void norm_all_kernel(
        const float* __restrict__ lcs, const float* __restrict__ fa,
        const float* __restrict__ fb, const float* __restrict__ fi,
        const float* __restrict__ fc, const float* __restrict__ fbk,
        float* __restrict__ ws) {
    int b = blockIdx.x;
    const float* src; float* dst; int len4; int recip = 1;
    float* rn = ws + OFF_RN;
    if (b < 4096) {
        src = lcs + (size_t)b * 2048; dst = rn + b; len4 = 512;
    } else if (b < 20480) {
        int region = (b - 4096) >> 12;     // 0 fa_lo, 1 fa_hi, 2 fb_lo, 3 fb_hi
        int r = (b - 4096) & 4095;
        const float* base = (region < 2) ? fa : fb;
        src = base + (size_t)r * 2048 + (region & 1) * 1024;
        dst = rn + b; len4 = 256;
    } else {
        int r = b - 20480;
        const float* base = (r < 32) ? fi : (r < 64 ? fc : fbk);
        src = base + (size_t)(r & 31) * 2048;
        dst = ws + OFF_NFEAT + r; len4 = 512; recip = 0;
    }
    const float4* p = (const float4*)src;
    float s = 0.f;
    for (int i = threadIdx.x; i < len4; i += 64) {
        float4 v = p[i];
        s += v.x * v.x + v.y * v.y + v.z * v.z + v.w * v.w;
    }
    #pragma unroll
    for (int off = 32; off; off >>= 1) s += __shfl_down(s, off);
    if (threadIdx.x == 0) *dst = recip ? rsqrtf(s) : sqrtf(s);
}

// ---------------- MFMA similarity kernel (K-split, raw partials) ----------------
// 256 blocks: 0..127 LCS (job=bid>>2, kslice=bid&3), 128..255 FSD (fj=(bid-128)>>1,
// kslice=(bid-128)&1). Every block does 8 K-steps of BK=64, reg-dbuf pipelined.
__global__ __launch_bounds__(256) void sim_mfma_kernel(
        const float* __restrict__ lcs, const float* __restrict__ fa,
        const float* __restrict__ fb, const int* __restrict__ pos,
        const int* __restrict__ neg, float* __restrict__ ws) {
    int bid = blockIdx.x;
    const float *Aptr, *Bptr;
    float* out;

    if (bid < 128) {
        int job = bid >> 2, ks = bid & 3;
        int pi = job & 15;
        const int* pp = (job >= 16) ? neg : pos;
        int p0 = pp[2 * pi], p1 = pp[2 * pi + 1];
        Aptr = lcs + (size_t)p0 * L_ * D_ + ks * 512;
        Bptr = lcs + (size_t)p1 * L_ * D_ + ks * 512;
        out = ws + OFF_LCS_PART + ((size_t)ks * 32 + job) * 16384;
    } else {
        int e = bid - 128;                 // 0..127
        int fj = e >> 1, ks = e & 1;       // fj 0..63
        int isneg = fj >= 32;
        int q = fj & 31;
        int pi = q >> 1, half = q & 1;
        const int* pp = isneg ? neg : pos;
        int p0 = pp[2 * pi], p1 = pp[2 * pi + 1];
        const float* Bbase = isneg ? fb : fa;
        Aptr = fa + (size_t)p0 * L_ * D_ + half * 1024 + ks * 512;
        Bptr = Bbase + (size_t)p1 * L_ * D_ + half * 1024 + ks * 512;
        int slot = (isneg ? 16 : 0) + pi;
        out = ws + (half ? OFF_G_PART : OFF_M_PART) + ((size_t)ks * 32 + slot) * 16384;
    }

    __shared__ ushort lA[2][128 * 64];
    __shared__ ushort lB[2][128 * 64];
    int tid = threadIdx.x;
    int lane = tid & 63;
    int w = tid >> 6;
    int wr = w >> 1, wc = w & 1;
    int lrow = lane & 15, lhk = lane >> 4;

    // per-thread staging slots (row = c>>3, kb = c&7 for c = tid + i*256)
    int srow[4], skb[4];
    #pragma unroll
    for (int i = 0; i < 4; ++i) {
        int c = tid + i * 256;
        srow[i] = c >> 3; skb[i] = c & 7;
    }

    float4 pa0[4], pa1[4], pb0[4], pb1[4];

    f32x4 acc[4][4];
    #pragma unroll
    for (int m = 0; m < 4; ++m)
        #pragma unroll
        for (int n = 0; n < 4; ++n)
            acc[m][n] = (f32x4){0.f, 0.f, 0.f, 0.f};

    // prologue: load + stage tile 0 into buf 0
    #pragma unroll
    for (int i = 0; i < 4; ++i) {
        const float* sA = Aptr + (size_t)srow[i] * D_ + skb[i] * 8;
        pa0[i] = *(const float4*)sA; pa1[i] = *(const float4*)(sA + 4);
        const float* sB = Bptr + (size_t)srow[i] * D_ + skb[i] * 8;
        pb0[i] = *(const float4*)sB; pb1[i] = *(const float4*)(sB + 4);
    }
    #pragma unroll
    for (int i = 0; i < 4; ++i) {
        int idx = ((srow[i] * 64 + skb[i] * 8) ^ ((srow[i] & 7) << 3));
        bf16x8 sv, sw;
        sv[0] = (short)f2bf(pa0[i].x); sv[1] = (short)f2bf(pa0[i].y);
        sv[2] = (short)f2bf(pa0[i].z); sv[3] = (short)f2bf(pa0[i].w);
        sv[4] = (short)f2bf(pa1[i].x); sv[5] = (short)f2bf(pa1[i].y);
        sv[6] = (short)f2bf(pa1[i].z); sv[7] = (short)f2bf(pa1[i].w);
        *(bf16x8*)&lA[0][idx] = sv;
        sw[0] = (short)f2bf(pb0[i].x); sw[1] = (short)f2bf(pb0[i].y);
        sw[2] = (short)f2bf(pb0[i].z); sw[3] = (short)f2bf(pb0[i].w);
        sw[4] = (short)f2bf(pb1[i].x); sw[5] = (short)f2bf(pb1[i].y);
        sw[6] = (short)f2bf(pb1[i].z); sw[7] = (short)f2bf(pb1[i].w);
        *(bf16x8*)&lB[0][idx] = sw;
    }
    __syncthreads();

    #pragma unroll
    for (int t = 0; t < 8; ++t) {
        // issue next tile's global loads (overlap with MFMA below)
        if (t < 7) {
            int k0 = (t + 1) * 64;
            #pragma unroll
            for (int i = 0; i < 4; ++i) {
                const float* sA = Aptr + (size_t)srow[i] * D_ + k0 + skb[i] * 8;
                pa0[i] = *(const float4*)sA; pa1[i] = *(const float4*)(sA + 4);
                const float* sB = Bptr + (size_t)srow[i] * D_ + k0 + skb[i] * 8;
                pb0[i] = *(const float4*)sB; pb1[i] = *(const float4*)(sB + 4);
            }
        }
        // MFMA on buf t&1
        #pragma unroll
        for (int ks = 0; ks < 2; ++ks) {
            int kbase = ks * 32 + lhk * 8;
            bf16x8 afr[4], bfr[4];
            #pragma unroll
            for (int m = 0; m < 4; ++m) {
                int row = wr * 64 + m * 16 + lrow;
                int idx = ((row * 64 + kbase) ^ ((row & 7) << 3));
                afr[m] = *(const bf16x8*)&lA[t & 1][idx];
            }
            #pragma unroll
            for (int n = 0; n < 4; ++n) {
                int row = wc * 64 + n * 16 + lrow;
                int idx = ((row * 64 + kbase) ^ ((row & 7) << 3));
                bfr[n] = *(const bf16x8*)&lB[t & 1][idx];
            }
            #pragma unroll
            for (int m = 0; m < 4; ++m)
                #pragma unroll
                for (int n = 0; n < 4; ++n)
                    acc[m][n] = __builtin_amdgcn_mfma_f32_16x16x32_bf16(
                        afr[m], bfr[n], acc[m][n], 0, 0, 0);
        }
        // convert + write next tile into other buffer
        if (t < 7) {
            #pragma unroll
            for (int i = 0; i < 4; ++i) {
                int idx = ((srow[i] * 64 + skb[i] * 8) ^ ((srow[i] & 7) << 3));
                bf16x8 sv, sw;
                sv[0] = (short)f2bf(pa0[i].x); sv[1] = (short)f2bf(pa0[i].y);
                sv[2] = (short)f2bf(pa0[i].z); sv[3] = (short)f2bf(pa0[i].w);
                sv[4] = (short)f2bf(pa1[i].x); sv[5] = (short)f2bf(pa1[i].y);
                sv[6] = (short)f2bf(pa1[i].z); sv[7] = (short)f2bf(pa1[i].w);
                *(bf16x8*)&lA[(t + 1) & 1][idx] = sv;
                sw[0] = (short)f2bf(pb0[i].x); sw[1] = (short)f2bf(pb0[i].y);
                sw[2] = (short)f2bf(pb0[i].z); sw[3] = (short)f2bf(pb0[i].w);
                sw[4] = (short)f2bf(pb1[i].x); sw[5] = (short)f2bf(pb1[i].y);
                sw[6] = (short)f2bf(pb1[i].z); sw[7] = (short)f2bf(pb1[i].w);
                *(bf16x8*)&lB[(t + 1) & 1][idx] = sw;
            }
        }
        __syncthreads();
    }

    // epilogue: raw partial dot products
    #pragma unroll
    for (int m = 0; m < 4; ++m) {
        #pragma unroll
        for (int n = 0; n < 4; ++n) {
            int jj = wc * 64 + n * 16 + lrow;
            #pragma unroll
            for (int r = 0; r < 4; ++r) {
                int ii = wr * 64 + m * 16 + lhk * 4 + r;
                out[ii * L_ + jj] = acc[m][n][r];
            }
        }
    }
}

// ---------------- fused DP kernel ----------------
// 64 blocks x 64 threads. blocks 0..31: LCS jobs; 32..63: FSD jobs.
// phase 1: reduce K-partials + normalize (+threshold for LCS) into LDS.
// phase 2: wave-synchronous skewed DP, lane l owns rows 2l, 2l+1.
__global__ __launch_bounds__(64) void dp_kernel(const int* __restrict__ pos,
                                                const int* __restrict__ neg,
                                                float* __restrict__ ws) {
    __shared__ float Sm[128 * 128];
    __shared__ float Sg[128 * 128];
    int job = blockIdx.x;
    int lane = threadIdx.x;
    const float* rn = ws + OFF_RN;
    bool is_lcs = job < 32;

    if (is_lcs) {
        int pi = job & 15;
        const int* pp = (job >= 16) ? neg : pos;
        int p0 = pp[2 * pi], p1 = pp[2 * pi + 1];
        const float* P = ws + OFF_LCS_PART + (size_t)job * 16384;
        const float* rA = rn + p0 * 128;
        const float* rB = rn + p1 * 128;
        for (int c = 0; c < 64; ++c) {
            int base = (c * 64 + lane) * 4;
            int r = base >> 7, j0 = base & 127;
            float4 v0 = *(const float4*)&P[base];
            float4 v1 = *(const float4*)&P[SLICE_STRIDE + base];
            float4 v2 = *(const float4*)&P[2 * SLICE_STRIDE + base];
            float4 v3 = *(const float4*)&P[3 * SLICE_STRIDE + base];
            float ra = rA[r];
            float4 rb = *(const float4*)&rB[j0];
            float4 sv;
            sv.x = fmaxf(((v0.x + v1.x + v2.x + v3.x) * ra * rb.x - 0.8f) * 5.f, 0.f);
            sv.y = fmaxf(((v0.y + v1.y + v2.y + v3.y) * ra * rb.y - 0.8f) * 5.f, 0.f);
            sv.z = fmaxf(((v0.z + v1.z + v2.z + v3.z) * ra * rb.z - 0.8f) * 5.f, 0.f);
            sv.w = fmaxf(((v0.w + v1.w + v2.w + v3.w) * ra * rb.w - 0.8f) * 5.f, 0.f);
            *(float4*)&Sm[base] = sv;
        }
    } else {
        int fj = job - 32;                 // 0..31: 0..15 pos, 16..31 neg
        int isneg = fj >= 16;
        int pi = fj & 15;
        const int* pp = isneg ? neg : pos;
        int p0 = pp[2 * pi], p1 = pp[2 * pi + 1];
        const float* Pm = ws + OFF_M_PART + (size_t)fj * 16384;
        const float* Pg = ws + OFF_G_PART + (size_t)fj * 16384;
        const float* rAm = rn + 4096 + p0 * 128;
        const float* rBm = rn + (isneg ? 12288 : 4096) + p1 * 128;
        const float* rAg = rn + 8192 + p0 * 128;
        const float* rBg = rn + (isneg ? 16384 : 8192) + p1 * 128;
        for (int c = 0; c < 64; ++c) {
            int base = (c * 64 + lane) * 4;
            int r = base >> 7, j0 = base & 127;
            float4 m0 = *(const float4*)&Pm[base];
            float4 m1 = *(const float4*)&Pm[SLICE_STRIDE + base];
            float4 g0 = *(const float4*)&Pg[base];
            float4 g1 = *(const float4*)&Pg[SLICE_STRIDE + base];
            float ram = rAm[r], rag = rAg[r];
            float4 rbm = *(const float4*)&rBm[j0];
            float4 rbg = *(const float4*)&rBg[j0];
            float4 mv, gv;
            mv.x = (m0.x + m1.x) * ram * rbm.x;
            mv.y = (m0.y + m1.y) * ram * rbm.y;
            mv.z = (m0.z + m1.z) * ram * rbm.z;
            mv.w = (m0.w + m1.w) * ram * rbm.w;
            gv.x = (g0.x + g1.x) * rag * rbg.x;
            gv.y = (g0.y + g1.y) * rag * rbg.y;
            gv.z = (g0.z + g1.z) * rag * rbg.z;
            gv.w = (g0.w + g1.w) * rag * rbg.w;
            *(float4*)&Sm[base] = mv;
            *(float4*)&Sg[base] = gv;
        }
    }
    __syncthreads();

    int ra = 2 * lane, rb = 2 * lane + 1;
    float a = 0.f, a_prev = 0.f, b = 0.f, u_prev = 0.f;

    if (is_lcs) {
        const float* Sa = Sm + ra * 128;
        const float* Sb = Sm + rb * 128;
        float sa_buf[4], sb_buf[4];
        #pragma unroll
        for (int p = 0; p < 4; ++p) {
            sa_buf[p] = Sa[min(max(p - ra, 0), 127)];
            sb_buf[p] = Sb[min(max(p - rb, 0), 127)];
        }
        #pragma unroll 4
        for (int t = 0; t < 256; ++t) {
            int slot = t & 3;
            float sa = sa_buf[slot], sb = sb_buf[slot];
            int ja = t - ra, jb = t - rb;
            float u = __shfl_up(b, 1);
            if (lane == 0) u = 0.f;
            float newa = (sa > 0.5f) ? (u_prev + sa) : fmaxf(u, a);
            float newb = (sb > 0.5f) ? (a_prev + sb) : fmaxf(a, b);
            a_prev = a;
            if (ja >= 0 && ja < 128) a = newa;
            if (jb >= 0 && jb < 128) b = newb;
            u_prev = u;
            sa_buf[slot] = Sa[min(max(t + 4 - ra, 0), 127)];
            sb_buf[slot] = Sb[min(max(t + 4 - rb, 0), 127)];
        }
        if (lane == 63) ws[OFF_LCS_RES + job] = b;
    } else {
        const float* Ma = Sm + ra * 128; const float* Mb = Sm + rb * 128;
        const float* Ga = Sg + ra * 128; const float* Gb = Sg + rb * 128;
        float mab[4], gab[4], mbb[4], gbb[4];
        #pragma unroll
        for (int p = 0; p < 4; ++p) {
            int ja = min(max(p - ra, 0), 127), jb = min(max(p - rb, 0), 127);
            mab[p] = Ma[ja]; gab[p] = Ga[ja];
            mbb[p] = Mb[jb]; gbb[p] = Gb[jb];
        }
        #pragma unroll 4
        for (int t = 0; t < 256; ++t) {
            int slot = t & 3;
            float ma = mab[slot], ga = gab[slot], mb = mbb[slot], gb = gbb[slot];
            int ja = t - ra, jb = t - rb;
            float u = __shfl_up(b, 1);
            if (lane == 0) u = 0.f;
            float x0 = u_prev, x1 = ga + u, x2 = ga + a;
            float mx = fmaxf(x0, fmaxf(x1, x2));
            float e0 = __expf((x0 - mx) * 10.f);
            float e1 = __expf((x1 - mx) * 10.f);
            float e2 = __expf((x2 - mx) * 10.f);
            float newa = ma + mx + 0.1f * __logf(e0 + e1 + e2);
            float y0 = a_prev, y1 = gb + a, y2 = gb + b;
            float my = fmaxf(y0, fmaxf(y1, y2));
            float f0 = __expf((y0 - my) * 10.f);
            float f1 = __expf((y1 - my) * 10.f);
            float f2 = __expf((y2 - my) * 10.f);
            float newb = mb + my + 0.1f * __logf(f0 + f1 + f2);
            a_prev = a;
            if (ja >= 0 && ja < 128) a = newa;
            if (jb >= 0 && jb < 128) b = newb;
            u_prev = u;
            int jan = min(max(t + 4 - ra, 0), 127), jbn = min(max(t + 4 - rb, 0), 127);
            mab[slot] = Ma[jan]; gab[slot] = Ga[jan];
            mbb[slot] = Mb[jbn]; gbb[slot] = Gb[jbn];
        }
        if (lane == 63) ws[OFF_FSD_RES + (job - 32)] = b;
    }
}

// ---------------- guide + sparse (LDS-staged, coalesced) ----------------
// 256 blocks x 256 threads; block handles 256 consecutive (b,t) elements.
__global__ __launch_bounds__(256) void guide_sparse_kernel(const float* __restrict__ att,
                                                           const float* __restrict__ cas,
                                                           float* __restrict__ acc) {
    __shared__ float sc[256 * 21];
    __shared__ float sa[256 * 3];
    int tid = threadIdx.x;
    size_t b0 = (size_t)blockIdx.x * 256;
    const float4* pc = (const float4*)(cas + b0 * 21);
    for (int i = tid; i < 1344; i += 256) *(float4*)&sc[i * 4] = pc[i];
    const float4* pa = (const float4*)(att + b0 * 3);
    for (int i = tid; i < 192; i += 256) *(float4*)&sa[i * 4] = pa[i];
    __syncthreads();
    float a0 = sa[tid * 3], a1 = sa[tid * 3 + 1];
    float g = fabsf(1.f - sc[tid * 21 + 20] - a0);
    float sp = a0 + a1;
    #pragma unroll
    for (int off = 32; off; off >>= 1) {
        g += __shfl_down(g, off);
        sp += __shfl_down(sp, off);
    }
    if ((tid & 63) == 0) {
        atomicAdd(&acc[0], g);
        atomicAdd(&acc[1], sp);
    }
}

// ---------------- final combine (1 block, 64 threads) ----------------
__global__ __launch_bounds__(64) void final_kernel(const float* __restrict__ xi,
                                                   const float* __restrict__ xc,
                                                   const float* __restrict__ xb,
                                                   const float* __restrict__ vl,
                                                   const float* __restrict__ ws,
                                                   float* __restrict__ out) {
    const float* nfeat = ws + OFF_NFEAT;
    const float* lcs_res = ws + OFF_LCS_RES;
    const float* fsd_res = ws + OFF_FSD_RES;
    const float* acc = ws + OFF_ACC;
    int lane = threadIdx.x;
    float part = 0.f;

    if (lane < B_) {
        int b = lane;
        float sv = 0.f;
        for (int j = 0; j < NCLS_; ++j) sv += vl[b * NCLS_ + j];
        float inv_i = 1.f / sv;
        float inv_c = 1.f / (sv + 1.f);
        float si = 0.f, sc = 0.f;
        for (int j = 0; j < NCLS_; ++j) {
            float lab = vl[b * NCLS_ + j];
            if (lab != 0.f) {
                si += logf(xi[b * (NCLS_ + 1) + j] + 1e-45f) * lab * inv_i;
                sc += logf(xc[b * (NCLS_ + 1) + j] + 1e-45f) * lab * inv_c;
            }
        }
        sc += logf(xc[b * (NCLS_ + 1) + NCLS_] + 1e-45f) * inv_c;
        float sb = logf(xb[b * (NCLS_ + 1) + NCLS_] + 1e-45f);
        float cls = -(si + sc + sb) / (float)B_;

        float ni = nfeat[b], nc = nfeat[B_ + b], nb = nfeat[2 * B_ + b];
        float f1 = fmaxf(50.f - ni + nc, 0.f);
        float f2 = fmaxf(50.f - nc + nb, 0.f);
        float fv = f1 + f2 + nb;
        float feat = fv * fv / (float)B_;

        float sgn = (b < NPAIR) ? -1.f : 1.f;
        float lcs = sgn * lcs_res[b] / (float)NPAIR;
        float fsd = sgn * fsd_res[b] / (float)NPAIR;

        part = cls + 5e-5f * feat + 0.1f * (lcs + fsd);
    }
    #pragma unroll
    for (int off = 32; off; off >>= 1) part += __shfl_down(part, off);
    if (lane == 0) {
        float guide = acc[0] / (float)B_;
        float sparse = acc[1] / (float)B_;
        out[0] = part + guide + 2e-4f * sparse;
    }
}

// ---------------- launcher ----------------
extern "C" void kernel_launch(void* const* d_in, const int* in_sizes, int n_in,
                              void* d_out, int out_size, void* d_ws, size_t ws_size,
                              hipStream_t stream) {
    const float* act_inst_cls = (const float*)d_in[0];
    const float* act_cont_cls = (const float*)d_in[1];
    const float* act_back_cls = (const float*)d_in[2];
    const float* vid_label    = (const float*)d_in[3];
    const float* temp_att     = (const float*)d_in[4];
    const float* act_inst_feat= (const float*)d_in[5];
    const float* act_cont_feat= (const float*)d_in[6];
    const float* act_back_feat= (const float*)d_in[7];
    const float* temp_cas     = (const float*)d_in[8];
    const float* lcs_candi    = (const float*)d_in[9];
    const float* fsd_act      = (const float*)d_in[10];
    const float* fsd_bak      = (const float*)d_in[11];
    const int*   pos_pair     = (const int*)d_in[12];
    const int*   neg_pair     = (const int*)d_in[13];

    float* ws = (float*)d_ws;
    float* out = (float*)d_out;

    hipMemsetAsync(ws + OFF_ACC, 0, 2 * sizeof(float), stream);

    hipLaunchKernelGGL(sim_mfma_kernel, dim3(256), dim3(256), 0, stream,
                       lcs_candi, fsd_act, fsd_bak, pos_pair, neg_pair, ws);

    hipLaunchKernelGGL(norm_all_kernel, dim3(20576), dim3(64), 0, stream,
                       lcs_candi, fsd_act, fsd_bak,
                       act_inst_feat, act_cont_feat, act_back_feat, ws);

    hipLaunchKernelGGL(guide_sparse_kernel, dim3(256), dim3(256), 0, stream,
                       temp_att, temp_cas, ws + OFF_ACC);

    hipLaunchKernelGGL(dp_kernel, dim3(64), dim3(64), 0, stream,
                       pos_pair, neg_pair, ws);

    hipLaunchKernelGGL(final_kernel, dim3(1), dim3(64), 0, stream,
                       act_inst_cls, act_cont_cls, act_back_cls, vid_label,
                       ws, out);
}

// Round 4
// 269.691 us; speedup vs baseline: 2.5823x; 1.0380x over previous
//
#include <hip/hip_runtime.h>
#include <hip/hip_bf16.h>
#include <math.h>

// ---------------- constants ----------------
#define B_    32
#define NCLS_ 20
#define T_    2048
#define D_    2048
#define L_    128
#define NPAIR 16

// ws layout (float offsets)
#define OFF_LCS_PART 0               // 4 slices * 32 jobs * 16384
#define OFF_M_PART   2097152         // 2 slices * 32 * 16384
#define OFF_G_PART   3145728         // 2 slices * 32 * 16384
#define OFF_RN       4194304         // 5 * 4096 (lcs, fa_lo, fa_hi, fb_lo, fb_hi)
#define OFF_NFEAT    4214784         // 96
#define OFF_LCS_RES  4214880         // 32
#define OFF_FSD_RES  4214912         // 32
#define OFF_ACC      4214944         // 2
#define SLICE_STRIDE 524288          // 32*16384

typedef __attribute__((ext_vector_type(8))) short bf16x8;
typedef __attribute__((ext_vector_type(4))) float f32x4;

__device__ __forceinline__ ushort f2bf(float f) {
    __hip_bfloat16 h = __float2bfloat16(f);
    return *reinterpret_cast<ushort*>(&h);
}

// ---------------- fused row-norm + guide/sparse kernel ----------------
// blocks 0..4095       : lcs rows, full D, rsqrt
// blocks 4096..20479   : fsd halves, rsqrt
// blocks 20480..20575  : feat rows, sqrt
// blocks 20576..21599  : guide/sparse, 64 (b,t) elements each
__global__ __launch_bounds__(64) void norm_guide_kernel(
        const float* __restrict__ lcs, const float* __restrict__ fa,
        const float* __restrict__ fb, const float* __restrict__ fi,
        const float* __restrict__ fc, const float* __restrict__ fbk,
        const float* __restrict__ att, const float* __restrict__ cas,
        float* __restrict__ ws) {
    __shared__ float sc[64 * 21 + 64 * 3];
    int b = blockIdx.x;
    int tid = threadIdx.x;

    if (b >= 20576) {
        // ---- guide/sparse region ----
        float* sa = sc + 64 * 21;
        size_t e0 = (size_t)(b - 20576) * 64;
        const float4* pc = (const float4*)(cas + e0 * 21);
        #pragma unroll
        for (int i = 0; i < 6; ++i) {
            int idx = tid + i * 64;
            if (idx < 336) *(float4*)&sc[idx * 4] = pc[idx];
        }
        const float4* pa = (const float4*)(att + e0 * 3);
        if (tid < 48) *(float4*)&sa[tid * 4] = pa[tid];
        __syncthreads();
        float a0 = sa[tid * 3], a1 = sa[tid * 3 + 1];
        float g = fabsf(1.f - sc[tid * 21 + 20] - a0);
        float sp = a0 + a1;
        #pragma unroll
        for (int off = 32; off; off >>= 1) {
            g += __shfl_down(g, off);
            sp += __shfl_down(sp, off);
        }
        if (tid == 0) {
            atomicAdd(&ws[OFF_ACC + 0], g);
            atomicAdd(&ws[OFF_ACC + 1], sp);
        }
        return;
    }

    const float* src; float* dst; int len4; int recip = 1;
    float* rn = ws + OFF_RN;
    if (b < 4096) {
        src = lcs + (size_t)b * 2048; dst = rn + b; len4 = 512;
    } else if (b < 20480) {
        int region = (b - 4096) >> 12;     // 0 fa_lo, 1 fa_hi, 2 fb_lo, 3 fb_hi
        int r = (b - 4096) & 4095;
        const float* base = (region < 2) ? fa : fb;
        src = base + (size_t)r * 2048 + (region & 1) * 1024;
        dst = rn + b; len4 = 256;
    } else {
        int r = b - 20480;
        const float* base = (r < 32) ? fi : (r < 64 ? fc : fbk);
        src = base + (size_t)(r & 31) * 2048;
        dst = ws + OFF_NFEAT + r; len4 = 512; recip = 0;
    }
    const float4* p = (const float4*)src;
    float s = 0.f;
    for (int i = tid; i < len4; i += 64) {
        float4 v = p[i];
        s += v.x * v.x + v.y * v.y + v.z * v.z + v.w * v.w;
    }
    #pragma unroll
    for (int off = 32; off; off >>= 1) s += __shfl_down(s, off);
    if (tid == 0) *dst = recip ? rsqrtf(s) : sqrtf(s);
}

// ---------------- MFMA similarity kernel (K-split, raw partials) ----------------
__global__ __launch_bounds__(256) void sim_mfma_kernel(
        const float* __restrict__ lcs, const float* __restrict__ fa,
        const float* __restrict__ fb, const int* __restrict__ pos,
        const int* __restrict__ neg, float* __restrict__ ws) {
    int bid = blockIdx.x;
    const float *Aptr, *Bptr;
    float* out;

    if (bid < 128) {
        int job = bid >> 2, ks = bid & 3;
        int pi = job & 15;
        const int* pp = (job >= 16) ? neg : pos;
        int p0 = pp[2 * pi], p1 = pp[2 * pi + 1];
        Aptr = lcs + (size_t)p0 * L_ * D_ + ks * 512;
        Bptr = lcs + (size_t)p1 * L_ * D_ + ks * 512;
        out = ws + OFF_LCS_PART + ((size_t)ks * 32 + job) * 16384;
    } else {
        int e = bid - 128;                 // 0..127
        int fj = e >> 1, ks = e & 1;       // fj 0..63
        int isneg = fj >= 32;
        int q = fj & 31;
        int pi = q >> 1, half = q & 1;
        const int* pp = isneg ? neg : pos;
        int p0 = pp[2 * pi], p1 = pp[2 * pi + 1];
        const float* Bbase = isneg ? fb : fa;
        Aptr = fa + (size_t)p0 * L_ * D_ + half * 1024 + ks * 512;
        Bptr = Bbase + (size_t)p1 * L_ * D_ + half * 1024 + ks * 512;
        int slot = (isneg ? 16 : 0) + pi;
        out = ws + (half ? OFF_G_PART : OFF_M_PART) + ((size_t)ks * 32 + slot) * 16384;
    }

    __shared__ ushort lA[2][128 * 64];
    __shared__ ushort lB[2][128 * 64];
    int tid = threadIdx.x;
    int lane = tid & 63;
    int w = tid >> 6;
    int wr = w >> 1, wc = w & 1;
    int lrow = lane & 15, lhk = lane >> 4;

    int srow[4], skb[4];
    #pragma unroll
    for (int i = 0; i < 4; ++i) {
        int c = tid + i * 256;
        srow[i] = c >> 3; skb[i] = c & 7;
    }

    float4 pa0[4], pa1[4], pb0[4], pb1[4];

    f32x4 acc[4][4];
    #pragma unroll
    for (int m = 0; m < 4; ++m)
        #pragma unroll
        for (int n = 0; n < 4; ++n)
            acc[m][n] = (f32x4){0.f, 0.f, 0.f, 0.f};

    #pragma unroll
    for (int i = 0; i < 4; ++i) {
        const float* sA = Aptr + (size_t)srow[i] * D_ + skb[i] * 8;
        pa0[i] = *(const float4*)sA; pa1[i] = *(const float4*)(sA + 4);
        const float* sB = Bptr + (size_t)srow[i] * D_ + skb[i] * 8;
        pb0[i] = *(const float4*)sB; pb1[i] = *(const float4*)(sB + 4);
    }
    #pragma unroll
    for (int i = 0; i < 4; ++i) {
        int idx = ((srow[i] * 64 + skb[i] * 8) ^ ((srow[i] & 7) << 3));
        bf16x8 sv, sw;
        sv[0] = (short)f2bf(pa0[i].x); sv[1] = (short)f2bf(pa0[i].y);
        sv[2] = (short)f2bf(pa0[i].z); sv[3] = (short)f2bf(pa0[i].w);
        sv[4] = (short)f2bf(pa1[i].x); sv[5] = (short)f2bf(pa1[i].y);
        sv[6] = (short)f2bf(pa1[i].z); sv[7] = (short)f2bf(pa1[i].w);
        *(bf16x8*)&lA[0][idx] = sv;
        sw[0] = (short)f2bf(pb0[i].x); sw[1] = (short)f2bf(pb0[i].y);
        sw[2] = (short)f2bf(pb0[i].z); sw[3] = (short)f2bf(pb0[i].w);
        sw[4] = (short)f2bf(pb1[i].x); sw[5] = (short)f2bf(pb1[i].y);
        sw[6] = (short)f2bf(pb1[i].z); sw[7] = (short)f2bf(pb1[i].w);
        *(bf16x8*)&lB[0][idx] = sw;
    }
    __syncthreads();

    #pragma unroll
    for (int t = 0; t < 8; ++t) {
        if (t < 7) {
            int k0 = (t + 1) * 64;
            #pragma unroll
            for (int i = 0; i < 4; ++i) {
                const float* sA = Aptr + (size_t)srow[i] * D_ + k0 + skb[i] * 8;
                pa0[i] = *(const float4*)sA; pa1[i] = *(const float4*)(sA + 4);
                const float* sB = Bptr + (size_t)srow[i] * D_ + k0 + skb[i] * 8;
                pb0[i] = *(const float4*)sB; pb1[i] = *(const float4*)(sB + 4);
            }
        }
        #pragma unroll
        for (int ks = 0; ks < 2; ++ks) {
            int kbase = ks * 32 + lhk * 8;
            bf16x8 afr[4], bfr[4];
            #pragma unroll
            for (int m = 0; m < 4; ++m) {
                int row = wr * 64 + m * 16 + lrow;
                int idx = ((row * 64 + kbase) ^ ((row & 7) << 3));
                afr[m] = *(const bf16x8*)&lA[t & 1][idx];
            }
            #pragma unroll
            for (int n = 0; n < 4; ++n) {
                int row = wc * 64 + n * 16 + lrow;
                int idx = ((row * 64 + kbase) ^ ((row & 7) << 3));
                bfr[n] = *(const bf16x8*)&lB[t & 1][idx];
            }
            #pragma unroll
            for (int m = 0; m < 4; ++m)
                #pragma unroll
                for (int n = 0; n < 4; ++n)
                    acc[m][n] = __builtin_amdgcn_mfma_f32_16x16x32_bf16(
                        afr[m], bfr[n], acc[m][n], 0, 0, 0);
        }
        if (t < 7) {
            #pragma unroll
            for (int i = 0; i < 4; ++i) {
                int idx = ((srow[i] * 64 + skb[i] * 8) ^ ((srow[i] & 7) << 3));
                bf16x8 sv, sw;
                sv[0] = (short)f2bf(pa0[i].x); sv[1] = (short)f2bf(pa0[i].y);
                sv[2] = (short)f2bf(pa0[i].z); sv[3] = (short)f2bf(pa0[i].w);
                sv[4] = (short)f2bf(pa1[i].x); sv[5] = (short)f2bf(pa1[i].y);
                sv[6] = (short)f2bf(pa1[i].z); sv[7] = (short)f2bf(pa1[i].w);
                *(bf16x8*)&lA[(t + 1) & 1][idx] = sv;
                sw[0] = (short)f2bf(pb0[i].x); sw[1] = (short)f2bf(pb0[i].y);
                sw[2] = (short)f2bf(pb0[i].z); sw[3] = (short)f2bf(pb0[i].w);
                sw[4] = (short)f2bf(pb1[i].x); sw[5] = (short)f2bf(pb1[i].y);
                sw[6] = (short)f2bf(pb1[i].z); sw[7] = (short)f2bf(pb1[i].w);
                *(bf16x8*)&lB[(t + 1) & 1][idx] = sw;
            }
        }
        __syncthreads();
    }

    #pragma unroll
    for (int m = 0; m < 4; ++m) {
        #pragma unroll
        for (int n = 0; n < 4; ++n) {
            int jj = wc * 64 + n * 16 + lrow;
            #pragma unroll
            for (int r = 0; r < 4; ++r) {
                int ii = wr * 64 + m * 16 + lhk * 4 + r;
                out[ii * L_ + jj] = acc[m][n][r];
            }
        }
    }
}

// ---------------- fused reduce+DP kernel ----------------
// 64 blocks x 256 threads. blocks 0..31 LCS, 32..63 FSD.
// phase 1 (256 thr): reduce K-partials + normalize (+threshold) into LDS.
// phase 2 (wave 0): skewed DP, lane l owns rows l and 64+l (bank-conflict-free).
__global__ __launch_bounds__(256) void dp_kernel(const int* __restrict__ pos,
                                                 const int* __restrict__ neg,
                                                 float* __restrict__ ws) {
    __shared__ float Sm[128 * 128];
    __shared__ float Sg[128 * 128];
    int job = blockIdx.x;
    int tid = threadIdx.x;
    const float* rn = ws + OFF_RN;
    bool is_lcs = job < 32;

    if (is_lcs) {
        int pi = job & 15;
        const int* pp = (job >= 16) ? neg : pos;
        int p0 = pp[2 * pi], p1 = pp[2 * pi + 1];
        const float* P = ws + OFF_LCS_PART + (size_t)job * 16384;
        const float* rA = rn + p0 * 128;
        const float* rB = rn + p1 * 128;
        #pragma unroll
        for (int c = 0; c < 16; ++c) {
            int base = (c * 256 + tid) * 4;
            int r = base >> 7, j0 = base & 127;
            float4 v0 = *(const float4*)&P[base];
            float4 v1 = *(const float4*)&P[SLICE_STRIDE + base];
            float4 v2 = *(const float4*)&P[2 * SLICE_STRIDE + base];
            float4 v3 = *(const float4*)&P[3 * SLICE_STRIDE + base];
            float ra = rA[r];
            float4 rb = *(const float4*)&rB[j0];
            float4 sv;
            sv.x = fmaxf(((v0.x + v1.x + v2.x + v3.x) * ra * rb.x - 0.8f) * 5.f, 0.f);
            sv.y = fmaxf(((v0.y + v1.y + v2.y + v3.y) * ra * rb.y - 0.8f) * 5.f, 0.f);
            sv.z = fmaxf(((v0.z + v1.z + v2.z + v3.z) * ra * rb.z - 0.8f) * 5.f, 0.f);
            sv.w = fmaxf(((v0.w + v1.w + v2.w + v3.w) * ra * rb.w - 0.8f) * 5.f, 0.f);
            *(float4*)&Sm[base] = sv;
        }
    } else {
        int fj = job - 32;
        int isneg = fj >= 16;
        int pi = fj & 15;
        const int* pp = isneg ? neg : pos;
        int p0 = pp[2 * pi], p1 = pp[2 * pi + 1];
        const float* Pm = ws + OFF_M_PART + (size_t)fj * 16384;
        const float* Pg = ws + OFF_G_PART + (size_t)fj * 16384;
        const float* rAm = rn + 4096 + p0 * 128;
        const float* rBm = rn + (isneg ? 12288 : 4096) + p1 * 128;
        const float* rAg = rn + 8192 + p0 * 128;
        const float* rBg = rn + (isneg ? 16384 : 8192) + p1 * 128;
        #pragma unroll
        for (int c = 0; c < 16; ++c) {
            int base = (c * 256 + tid) * 4;
            int r = base >> 7, j0 = base & 127;
            float4 m0 = *(const float4*)&Pm[base];
            float4 m1 = *(const float4*)&Pm[SLICE_STRIDE + base];
            float4 g0 = *(const float4*)&Pg[base];
            float4 g1 = *(const float4*)&Pg[SLICE_STRIDE + base];
            float ram = rAm[r], rag = rAg[r];
            float4 rbm = *(const float4*)&rBm[j0];
            float4 rbg = *(const float4*)&rBg[j0];
            float4 mv, gv;
            mv.x = (m0.x + m1.x) * ram * rbm.x;
            mv.y = (m0.y + m1.y) * ram * rbm.y;
            mv.z = (m0.z + m1.z) * ram * rbm.z;
            mv.w = (m0.w + m1.w) * ram * rbm.w;
            gv.x = (g0.x + g1.x) * rag * rbg.x;
            gv.y = (g0.y + g1.y) * rag * rbg.y;
            gv.z = (g0.z + g1.z) * rag * rbg.z;
            gv.w = (g0.w + g1.w) * rag * rbg.w;
            *(float4*)&Sm[base] = mv;
            *(float4*)&Sg[base] = gv;
        }
    }
    __syncthreads();

    if (tid >= 64) return;
    int l = tid;
    const float* SA = Sm + l * 128;            // row l
    const float* SB = Sm + (64 + l) * 128;     // row 64+l
    float a = 0.f, b = 0.f, ua_prev = 0.f, ub_prev = 0.f;

    if (is_lcs) {
        float sa_buf[4], sb_buf[4];
        #pragma unroll
        for (int p = 0; p < 4; ++p) {
            sa_buf[p] = SA[min(max(p - l, 0), 127)];
            sb_buf[p] = SB[min(max(p - 64 - l, 0), 127)];
        }
        #pragma unroll 4
        for (int t = 0; t < 256; ++t) {
            int slot = t & 3;
            float sa = sa_buf[slot], sb = sb_buf[slot];
            float ua = __shfl_up(a, 1);
            float a63 = __shfl(a, 63);
            float ub = __shfl_up(b, 1);
            if (l == 0) { ua = 0.f; ub = a63; }
            int ja = t - l, jb = t - 64 - l;
            float newa = (sa > 0.5f) ? (ua_prev + sa) : fmaxf(ua, a);
            float newb = (sb > 0.5f) ? (ub_prev + sb) : fmaxf(ub, b);
            if (ja >= 0 && ja < 128) a = newa;
            if (jb >= 0 && jb < 128) b = newb;
            ua_prev = ua; ub_prev = ub;
            sa_buf[slot] = SA[min(max(t + 4 - l, 0), 127)];
            sb_buf[slot] = SB[min(max(t + 4 - 64 - l, 0), 127)];
        }
        if (l == 63) ws[OFF_LCS_RES + job] = b;
    } else {
        const float* GA = Sg + l * 128;
        const float* GB = Sg + (64 + l) * 128;
        float mab[4], gab[4], mbb[4], gbb[4];
        #pragma unroll
        for (int p = 0; p < 4; ++p) {
            int ja = min(max(p - l, 0), 127), jb = min(max(p - 64 - l, 0), 127);
            mab[p] = SA[ja]; gab[p] = GA[ja];
            mbb[p] = SB[jb]; gbb[p] = GB[jb];
        }
        #pragma unroll 4
        for (int t = 0; t < 256; ++t) {
            int slot = t & 3;
            float ma = mab[slot], ga = gab[slot], mb = mbb[slot], gb = gbb[slot];
            float ua = __shfl_up(a, 1);
            float a63 = __shfl(a, 63);
            float ub = __shfl_up(b, 1);
            if (l == 0) { ua = 0.f; ub = a63; }
            int ja = t - l, jb = t - 64 - l;
            float x0 = ua_prev, x1 = ga + ua, x2 = ga + a;
            float mx = fmaxf(x0, fmaxf(x1, x2));
            float e0 = __expf((x0 - mx) * 10.f);
            float e1 = __expf((x1 - mx) * 10.f);
            float e2 = __expf((x2 - mx) * 10.f);
            float newa = ma + mx + 0.1f * __logf(e0 + e1 + e2);
            float y0 = ub_prev, y1 = gb + ub, y2 = gb + b;
            float my = fmaxf(y0, fmaxf(y1, y2));
            float f0 = __expf((y0 - my) * 10.f);
            float f1 = __expf((y1 - my) * 10.f);
            float f2 = __expf((y2 - my) * 10.f);
            float newb = mb + my + 0.1f * __logf(f0 + f1 + f2);
            if (ja >= 0 && ja < 128) a = newa;
            if (jb >= 0 && jb < 128) b = newb;
            ua_prev = ua; ub_prev = ub;
            int jan = min(max(t + 4 - l, 0), 127), jbn = min(max(t + 4 - 64 - l, 0), 127);
            mab[slot] = SA[jan]; gab[slot] = GA[jan];
            mbb[slot] = SB[jbn]; gbb[slot] = GB[jbn];
        }
        if (l == 63) ws[OFF_FSD_RES + (job - 32)] = b;
    }
}

// ---------------- final combine (1 block, 64 threads) ----------------
__global__ __launch_bounds__(64) void final_kernel(const float* __restrict__ xi,
                                                   const float* __restrict__ xc,
                                                   const float* __restrict__ xb,
                                                   const float* __restrict__ vl,
                                                   const float* __restrict__ ws,
                                                   float* __restrict__ out) {
    const float* nfeat = ws + OFF_NFEAT;
    const float* lcs_res = ws + OFF_LCS_RES;
    const float* fsd_res = ws + OFF_FSD_RES;
    const float* acc = ws + OFF_ACC;
    int lane = threadIdx.x;
    float part = 0.f;

    if (lane < B_) {
        int b = lane;
        float sv = 0.f;
        for (int j = 0; j < NCLS_; ++j) sv += vl[b * NCLS_ + j];
        float inv_i = 1.f / sv;
        float inv_c = 1.f / (sv + 1.f);
        float si = 0.f, sc = 0.f;
        for (int j = 0; j < NCLS_; ++j) {
            float lab = vl[b * NCLS_ + j];
            if (lab != 0.f) {
                si += logf(xi[b * (NCLS_ + 1) + j] + 1e-45f) * lab * inv_i;
                sc += logf(xc[b * (NCLS_ + 1) + j] + 1e-45f) * lab * inv_c;
            }
        }
        sc += logf(xc[b * (NCLS_ + 1) + NCLS_] + 1e-45f) * inv_c;
        float sb = logf(xb[b * (NCLS_ + 1) + NCLS_] + 1e-45f);
        float cls = -(si + sc + sb) / (float)B_;

        float ni = nfeat[b], nc = nfeat[B_ + b], nb = nfeat[2 * B_ + b];
        float f1 = fmaxf(50.f - ni + nc, 0.f);
        float f2 = fmaxf(50.f - nc + nb, 0.f);
        float fv = f1 + f2 + nb;
        float feat = fv * fv / (float)B_;

        float sgn = (b < NPAIR) ? -1.f : 1.f;
        float lcs = sgn * lcs_res[b] / (float)NPAIR;
        float fsd = sgn * fsd_res[b] / (float)NPAIR;

        part = cls + 5e-5f * feat + 0.1f * (lcs + fsd);
    }
    #pragma unroll
    for (int off = 32; off; off >>= 1) part += __shfl_down(part, off);
    if (lane == 0) {
        float guide = acc[0] / (float)B_;
        float sparse = acc[1] / (float)B_;
        out[0] = part + guide + 2e-4f * sparse;
    }
}

// ---------------- launcher ----------------
extern "C" void kernel_launch(void* const* d_in, const int* in_sizes, int n_in,
                              void* d_out, int out_size, void* d_ws, size_t ws_size,
                              hipStream_t stream) {
    const float* act_inst_cls = (const float*)d_in[0];
    const float* act_cont_cls = (const float*)d_in[1];
    const float* act_back_cls = (const float*)d_in[2];
    const float* vid_label    = (const float*)d_in[3];
    const float* temp_att     = (const float*)d_in[4];
    const float* act_inst_feat= (const float*)d_in[5];
    const float* act_cont_feat= (const float*)d_in[6];
    const float* act_back_feat= (const float*)d_in[7];
    const float* temp_cas     = (const float*)d_in[8];
    const float* lcs_candi    = (const float*)d_in[9];
    const float* fsd_act      = (const float*)d_in[10];
    const float* fsd_bak      = (const float*)d_in[11];
    const int*   pos_pair     = (const int*)d_in[12];
    const int*   neg_pair     = (const int*)d_in[13];

    float* ws = (float*)d_ws;
    float* out = (float*)d_out;

    hipMemsetAsync(ws + OFF_ACC, 0, 2 * sizeof(float), stream);

    hipLaunchKernelGGL(sim_mfma_kernel, dim3(256), dim3(256), 0, stream,
                       lcs_candi, fsd_act, fsd_bak, pos_pair, neg_pair, ws);

    hipLaunchKernelGGL(norm_guide_kernel, dim3(21600), dim3(64), 0, stream,
                       lcs_candi, fsd_act, fsd_bak,
                       act_inst_feat, act_cont_feat, act_back_feat,
                       temp_att, temp_cas, ws);

    hipLaunchKernelGGL(dp_kernel, dim3(64), dim3(256), 0, stream,
                       pos_pair, neg_pair, ws);

    hipLaunchKernelGGL(final_kernel, dim3(1), dim3(64), 0, stream,
                       act_inst_cls, act_cont_cls, act_back_cls, vid_label,
                       ws, out);
}